// Round 4
// baseline (446.663 us; speedup 1.0000x reference)
//
#include <hip/hip_runtime.h>
#include <math.h>

#define NN 10000
#define NE 160000
#define CAP 96   // per-node edge bin capacity; deg ~ Poisson(16), +20 sigma
// Only the l=0 irrep reaches the output (scal takes cols h*72..h*72+8 of pooled,
// which come solely from node_out[:,:,0]; Y[:,0]==1). l=1/l=2 paths are dead.
//
// Round 11: R10 structure with k_gather + k_pool + k_final fused into one
// kernel. Gather waves atomicAdd their 8 output channels directly into
// pooled[batch[n]] (skipping the feat array + 40-block pooling kernel);
// last-block ticket (validated R9/R10) runs the final 16x16 @ 16x32 matmul.
// 4 launches -> 3. k_xqk / k_edge byte-identical to R10.
//
// Workspace (floats):
//   x      [10000][16]        @ 0
//   q      [10000][2][16]     @ 160000
//   k      [10000][2][16]     @ 480000
//   pooled [16][16]           @ 800000
//   deg    int[10000]         @ 800256   (pooled..deg..done zeroed together)
//   done   int[16]            @ 810256
//   vC     [2][64][16]        @ 810272   (compacted Wv[:, ::3])
//   lgp    [10000][96][2]     fp32 logits
//   gb     [10000][96][2][4]  uint bf16x2-packed g[8] per head

__device__ __forceinline__ unsigned bf16pack2(float a, float b) {
    unsigned ua = __float_as_uint(a);
    unsigned ub = __float_as_uint(b);
    ua = ua + 0x7fffu + ((ua >> 16) & 1u);
    ub = ub + 0x7fffu + ((ub >> 16) & 1u);
    return (ua >> 16) | (ub & 0xffff0000u);
}

// x = nf @ We + be ; q[h] = x @ Wq[h] ; k[h] = x @ Wk[h]
// block 0 also compacts Wv -> vC; all blocks zero pooled+deg+done.
__global__ __launch_bounds__(256) void k_xqk(const float* __restrict__ nf,
        const float* __restrict__ We, const float* __restrict__ be,
        const float* __restrict__ Wq, const float* __restrict__ Wk,
        const float* __restrict__ Wv,
        float* __restrict__ x, float* __restrict__ q, float* __restrict__ k,
        int* __restrict__ zeroReg, float* __restrict__ vC) {
    int t = threadIdx.x;
    int gid = blockIdx.x * 256 + t;
    if (gid < 10272) zeroReg[gid] = 0;   // pooled(256f)+deg(10000i)+done(16i)
    if (blockIdx.x == 0) {
        for (int i = t; i < 2048; i += 256) {
            int h = i >> 10, j = (i >> 4) & 63, c = i & 15;
            vC[i] = Wv[(h * 64 + j) * 48 + 3 * c];
        }
    }
    __shared__ float sWe[64 * 16];
    __shared__ float sWq[2 * 16 * 16];
    __shared__ float sWk[2 * 16 * 16];
    __shared__ float sNF[16 * 64];
    __shared__ float sX[16 * 16];
    for (int i = t; i < 1024; i += 256) sWe[i] = We[i];
    for (int i = t; i < 512; i += 256) { sWq[i] = Wq[i]; sWk[i] = Wk[i]; }
    int nodeBase = blockIdx.x * 16;
    for (int i = t; i < 1024; i += 256) {
        int n = nodeBase + (i >> 6);
        sNF[i] = (n < NN) ? nf[n * 64 + (i & 63)] : 0.0f;
    }
    __syncthreads();
    int ln = t >> 4, c = t & 15;
    int n = nodeBase + ln;
    float acc = be[c];
    #pragma unroll 16
    for (int j = 0; j < 64; ++j) acc = fmaf(sNF[ln * 64 + j], sWe[j * 16 + c], acc);
    sX[ln * 16 + c] = acc;
    __syncthreads();
    if (n < NN) {
        x[n * 16 + c] = acc;
        #pragma unroll
        for (int h = 0; h < 2; ++h) {
            float aq = 0.0f, ak = 0.0f;
            #pragma unroll
            for (int j = 0; j < 16; ++j) {
                float xv = sX[ln * 16 + j];
                aq = fmaf(xv, sWq[(h * 16 + j) * 16 + c], aq);
                ak = fmaf(xv, sWk[(h * 16 + j) * 16 + c], ak);
            }
            q[(n * 2 + h) * 16 + c] = aq;
            k[(n * 2 + h) * 16 + c] = ak;
        }
    }
}

// one thread per edge: logits + g[o] = ((hid@V) * x[src]) @ Wo, bin slot tgt*CAP+p.
// Weight reads are lane-invariant -> scalar s_loads. Payload bf16x2-packed.
__global__ __launch_bounds__(256) void k_edge(const float* __restrict__ pos,
        const int* __restrict__ ei,
        const float* __restrict__ q, const float* __restrict__ k,
        const float* __restrict__ W1, const float* __restrict__ b1,
        const float* __restrict__ Wa, const float* __restrict__ vC,
        const float* __restrict__ Wo,
        const float* __restrict__ x, int* __restrict__ deg,
        float* __restrict__ lgp, uint4* __restrict__ gb) {
    int e = blockIdx.x * 256 + threadIdx.x;
    if (e >= NE) return;
    int s = ei[e], t = ei[NE + e];
    int p = atomicAdd(&deg[t], 1);
    bool ok = (p < CAP);
    size_t slot = (size_t)t * CAP + p;
    float dx = pos[t * 3 + 0] - pos[s * 3 + 0];
    float dy = pos[t * 3 + 1] - pos[s * 3 + 1];
    float dz = pos[t * 3 + 2] - pos[s * 3 + 2];
    float d = sqrtf(dx * dx + dy * dy + dz * dz);
    float fh[2] = { d, 1.0f / (d * d) };
    const float4* xp = (const float4*)(x + (size_t)s * 16);
    float4 xs0 = xp[0], xs1 = xp[1], xs2 = xp[2], xs3 = xp[3];
    float xf[16] = { xs0.x, xs0.y, xs0.z, xs0.w, xs1.x, xs1.y, xs1.z, xs1.w,
                     xs2.x, xs2.y, xs2.z, xs2.w, xs3.x, xs3.y, xs3.z, xs3.w };
    float L2v[2];
    #pragma unroll
    for (int h = 0; h < 2; ++h) {
        const float4* qt = (const float4*)(q + (size_t)t * 32 + h * 16);
        const float4* ks = (const float4*)(k + (size_t)s * 32 + h * 16);
        float4 a0 = qt[0], a1 = qt[1], a2 = qt[2], a3 = qt[3];
        float4 b0 = ks[0], c1 = ks[1], c2 = ks[2], c3 = ks[3];
        float dot = a0.x * b0.x + a0.y * b0.y + a0.z * b0.z + a0.w * b0.w
                  + a1.x * c1.x + a1.y * c1.y + a1.z * c1.z + a1.w * c1.w
                  + a2.x * c2.x + a2.y * c2.y + a2.z * c2.z + a2.w * c2.w
                  + a3.x * c3.x + a3.y * c3.y + a3.z * c3.z + a3.w * c3.w;
        float f = fh[h];
        float att = 0.0f;
        float acc[16];
        #pragma unroll
        for (int c = 0; c < 16; ++c) acc[c] = 0.0f;
        const float* w1b = W1 + h * 64;
        const float* b1b = b1 + h * 64;
        const float* wab = Wa + h * 64;
        const float* vcb = vC + h * 1024;
        #pragma unroll 8
        for (int j = 0; j < 64; ++j) {
            float hid = fmaxf(fmaf(f, w1b[j], b1b[j]), 0.0f);   // uniform scalars
            att = fmaf(hid, wab[j], att);
            #pragma unroll
            for (int c = 0; c < 16; ++c)
                acc[c] = fmaf(hid, vcb[j * 16 + c], acc[c]);     // uniform scalars
        }
        L2v[h] = fmaf(dot, 0.25f, att);
        // project to 8 outputs through Wo[h][0] (uniform scalars)
        float g[8];
        #pragma unroll
        for (int o = 0; o < 8; ++o) g[o] = 0.0f;
        const float* wob = Wo + h * 384;   // Wo[h][0][c][o] = Wo[h*384 + c*8 + o]
        #pragma unroll
        for (int c = 0; c < 16; ++c) {
            float axc = acc[c] * xf[c];
            #pragma unroll
            for (int o = 0; o < 8; ++o) g[o] = fmaf(axc, wob[c * 8 + o], g[o]);
        }
        if (ok) {
            gb[slot * 2 + h] = make_uint4(bf16pack2(g[0], g[1]), bf16pack2(g[2], g[3]),
                                          bf16pack2(g[4], g[5]), bf16pack2(g[6], g[7]));
        }
    }
    if (ok) *(float2*)(lgp + slot * 2) = make_float2(L2v[0], L2v[1]);
}

// wave per (node,head): 16 edge-groups x 4 lanes x 2 outputs (bf16x2 unpack),
// single-pass online softmax, -inf-safe merges. Result goes straight into
// pooled[batch[n]] via atomicAdd; last block (ticket) does the final matmul.
__global__ __launch_bounds__(256) void k_gatherpool(const int* __restrict__ deg,
        const float* __restrict__ lgp, const unsigned* __restrict__ gb,
        const int* __restrict__ batch, float* __restrict__ pooled,
        int* __restrict__ done, const float* __restrict__ Wproj,
        const float* __restrict__ bproj, float* __restrict__ out) {
    int t0 = threadIdx.x;
    int wv = t0 >> 6;                     // wave in block 0..3
    int lane = t0 & 63;
    int pid = blockIdx.x * 4 + wv;        // (node,head) pair; grid exact
    int n = pid >> 1, h = pid & 1;
    int dg = min(deg[n], CAP);
    int g = lane >> 2, p = lane & 3;      // group 0..15, uint index 0..3
    float m = -INFINITY, z = 0.0f, u0 = 0.0f, u1 = 0.0f;
    const float* lgb = lgp + (size_t)n * (CAP * 2) + h;
    const unsigned* gbb = gb + (size_t)n * (CAP * 8) + h * 4 + p;
    for (int i = g; i < dg; i += 16) {
        float L = lgb[i * 2];
        unsigned wbits = gbb[(size_t)i * 8];
        float ga = __uint_as_float(wbits << 16);
        float gbv = __uint_as_float(wbits & 0xffff0000u);
        float nm = fmaxf(m, L);
        float sc = (m > -INFINITY) ? __expf(m - nm) : 0.0f;
        float w  = __expf(L - nm);
        u0 = fmaf(u0, sc, w * ga);
        u1 = fmaf(u1, sc, w * gbv);
        z  = fmaf(z, sc, w);
        m = nm;
    }
    // merge the 16 groups (xor offs 4..32 preserve p bits)
    #pragma unroll
    for (int off = 4; off <= 32; off <<= 1) {
        float mo = __shfl_xor(m, off, 64);
        float zo = __shfl_xor(z, off, 64);
        float a0o = __shfl_xor(u0, off, 64);
        float a1o = __shfl_xor(u1, off, 64);
        float nm = fmaxf(m, mo);
        float a = (m  > -INFINITY) ? __expf(m  - nm) : 0.0f;
        float b = (mo > -INFINITY) ? __expf(mo - nm) : 0.0f;
        u0 = u0 * a + a0o * b;
        u1 = u1 * a + a1o * b;
        z  = z * a + zo * b;
        m = nm;
    }
    if (lane < 4) {
        float inv = (z > 0.0f) ? 1.0f / z : 0.0f;
        int grp = batch[n];
        float* dst = pooled + grp * 16 + h * 8 + p * 2;
        atomicAdd(dst + 0, u0 * inv);
        atomicAdd(dst + 1, u1 * inv);
    }
    __threadfence();
    __syncthreads();
    __shared__ int lastBlk;
    if (t0 == 0) lastBlk = (atomicAdd(done, 1) == 4999) ? 1 : 0;
    __syncthreads();
    if (!lastBlk) return;
    __shared__ float sPool[256];
    sPool[t0] = atomicAdd(&pooled[t0], 0.0f);   // coherent read of final values
    __syncthreads();
    for (int i = t0; i < 512; i += 256) {
        int gq = i >> 5, fo = i & 31;
        float acc = bproj[fo];
        #pragma unroll
        for (int j = 0; j < 16; ++j) acc = fmaf(sPool[gq * 16 + j], Wproj[j * 32 + fo], acc);
        out[gq * 32 + fo] = acc;
    }
}

extern "C" void kernel_launch(void* const* d_in, const int* in_sizes, int n_in,
                              void* d_out, int out_size, void* d_ws, size_t ws_size,
                              hipStream_t stream) {
    const float* nf    = (const float*)d_in[0];
    const float* pos   = (const float*)d_in[1];
    const float* We    = (const float*)d_in[2];
    const float* be    = (const float*)d_in[3];
    const float* Wq    = (const float*)d_in[4];
    const float* Wk    = (const float*)d_in[5];
    const float* W1    = (const float*)d_in[6];
    const float* b1    = (const float*)d_in[7];
    const float* Wa    = (const float*)d_in[8];
    const float* Wv    = (const float*)d_in[9];
    const float* Wo    = (const float*)d_in[10];
    const float* Wproj = (const float*)d_in[11];
    const float* bproj = (const float*)d_in[12];
    const int*   ei    = (const int*)d_in[13];
    const int*   batch = (const int*)d_in[14];
    float* out = (float*)d_out;
    (void)in_sizes; (void)n_in; (void)out_size; (void)ws_size;

    float* ws     = (float*)d_ws;
    float* x      = ws;                  // 160000
    float* q      = x + 160000;          // 320000
    float* k      = q + 320000;          // 320000
    float* pooled = k + 320000;          // 256
    int*   deg    = (int*)(pooled + 256);// 10000
    int*   done   = deg + 10000;         // 16
    float* vC     = (float*)(done + 16);         // 2048
    float* lgp    = vC + 2048;                   // 1,920,000
    unsigned* gbu = (unsigned*)(lgp + (size_t)NN * CAP * 2);  // 7,680,000 uints

    hipLaunchKernelGGL(k_xqk,       dim3(625),  dim3(256), 0, stream,
                       nf, We, be, Wq, Wk, Wv, x, q, k, (int*)pooled, vC);
    hipLaunchKernelGGL(k_edge,      dim3(625),  dim3(256), 0, stream,
                       pos, ei, q, k, W1, b1, Wa, vC, Wo, x, deg, lgp, (uint4*)gbu);
    hipLaunchKernelGGL(k_gatherpool, dim3(5000), dim3(256), 0, stream,
                       deg, lgp, gbu, batch, pooled, done, Wproj, bproj, out);
}

// Round 5
// 134.440 us; speedup vs baseline: 3.3224x; 3.3224x over previous
//
#include <hip/hip_runtime.h>
#include <math.h>

#define NN 10000
#define NE 160000
#define CAP 96   // per-node edge bin capacity; deg ~ Poisson(16), +20 sigma
// Only the l=0 irrep reaches the output (scal takes cols h*72..h*72+8 of pooled,
// which come solely from node_out[:,:,0]; Y[:,0]==1). l=1/l=2 paths are dead.
//
// Round 12: exact revert to the R10 structure (131.8 us; R7 band 130-132,
// reproduced 3x). R11's direct-to-pooled global atomics serialized on 16
// cache lines (341 us kernel, 34 ns/same-line L2 RMW) -> LDS pre-reduction
// is mandatory for the pool. Only change vs R10: k_poolfinal 40->80 blocks
// (8-node segments), halving its serial node loop; ticket constant 79.
//
// Workspace (floats):
//   x      [10000][16]        @ 0
//   q      [10000][2][16]     @ 160000
//   k      [10000][2][16]     @ 480000
//   feat   [10000][16]        @ 800000
//   pooled [16][16]           @ 960000
//   deg    int[10000]         @ 960256   (pooled..deg..done zeroed together)
//   done   int[16]            @ 970256
//   vC     [2][64][16]        @ 970272   (compacted Wv[:, ::3])
//   lgp    [10000][96][2]     fp32 logits
//   gb     [10000][96][2][4]  uint bf16x2-packed g[8] per head

__device__ __forceinline__ unsigned bf16pack2(float a, float b) {
    unsigned ua = __float_as_uint(a);
    unsigned ub = __float_as_uint(b);
    ua = ua + 0x7fffu + ((ua >> 16) & 1u);
    ub = ub + 0x7fffu + ((ub >> 16) & 1u);
    return (ua >> 16) | (ub & 0xffff0000u);
}

// x = nf @ We + be ; q[h] = x @ Wq[h] ; k[h] = x @ Wk[h]
// block 0 also compacts Wv -> vC; all blocks zero pooled+deg+done.
__global__ __launch_bounds__(256) void k_xqk(const float* __restrict__ nf,
        const float* __restrict__ We, const float* __restrict__ be,
        const float* __restrict__ Wq, const float* __restrict__ Wk,
        const float* __restrict__ Wv,
        float* __restrict__ x, float* __restrict__ q, float* __restrict__ k,
        int* __restrict__ zeroReg, float* __restrict__ vC) {
    int t = threadIdx.x;
    int gid = blockIdx.x * 256 + t;
    if (gid < 10272) zeroReg[gid] = 0;   // pooled(256f)+deg(10000i)+done(16i)
    if (blockIdx.x == 0) {
        for (int i = t; i < 2048; i += 256) {
            int h = i >> 10, j = (i >> 4) & 63, c = i & 15;
            vC[i] = Wv[(h * 64 + j) * 48 + 3 * c];
        }
    }
    __shared__ float sWe[64 * 16];
    __shared__ float sWq[2 * 16 * 16];
    __shared__ float sWk[2 * 16 * 16];
    __shared__ float sNF[16 * 64];
    __shared__ float sX[16 * 16];
    for (int i = t; i < 1024; i += 256) sWe[i] = We[i];
    for (int i = t; i < 512; i += 256) { sWq[i] = Wq[i]; sWk[i] = Wk[i]; }
    int nodeBase = blockIdx.x * 16;
    for (int i = t; i < 1024; i += 256) {
        int n = nodeBase + (i >> 6);
        sNF[i] = (n < NN) ? nf[n * 64 + (i & 63)] : 0.0f;
    }
    __syncthreads();
    int ln = t >> 4, c = t & 15;
    int n = nodeBase + ln;
    float acc = be[c];
    #pragma unroll 16
    for (int j = 0; j < 64; ++j) acc = fmaf(sNF[ln * 64 + j], sWe[j * 16 + c], acc);
    sX[ln * 16 + c] = acc;
    __syncthreads();
    if (n < NN) {
        x[n * 16 + c] = acc;
        #pragma unroll
        for (int h = 0; h < 2; ++h) {
            float aq = 0.0f, ak = 0.0f;
            #pragma unroll
            for (int j = 0; j < 16; ++j) {
                float xv = sX[ln * 16 + j];
                aq = fmaf(xv, sWq[(h * 16 + j) * 16 + c], aq);
                ak = fmaf(xv, sWk[(h * 16 + j) * 16 + c], ak);
            }
            q[(n * 2 + h) * 16 + c] = aq;
            k[(n * 2 + h) * 16 + c] = ak;
        }
    }
}

// one thread per edge: logits + g[o] = ((hid@V) * x[src]) @ Wo, bin slot tgt*CAP+p.
// Weight reads are lane-invariant -> scalar s_loads. Payload bf16x2-packed.
__global__ __launch_bounds__(256) void k_edge(const float* __restrict__ pos,
        const int* __restrict__ ei,
        const float* __restrict__ q, const float* __restrict__ k,
        const float* __restrict__ W1, const float* __restrict__ b1,
        const float* __restrict__ Wa, const float* __restrict__ vC,
        const float* __restrict__ Wo,
        const float* __restrict__ x, int* __restrict__ deg,
        float* __restrict__ lgp, uint4* __restrict__ gb) {
    int e = blockIdx.x * 256 + threadIdx.x;
    if (e >= NE) return;
    int s = ei[e], t = ei[NE + e];
    int p = atomicAdd(&deg[t], 1);
    bool ok = (p < CAP);
    size_t slot = (size_t)t * CAP + p;
    float dx = pos[t * 3 + 0] - pos[s * 3 + 0];
    float dy = pos[t * 3 + 1] - pos[s * 3 + 1];
    float dz = pos[t * 3 + 2] - pos[s * 3 + 2];
    float d = sqrtf(dx * dx + dy * dy + dz * dz);
    float fh[2] = { d, 1.0f / (d * d) };
    const float4* xp = (const float4*)(x + (size_t)s * 16);
    float4 xs0 = xp[0], xs1 = xp[1], xs2 = xp[2], xs3 = xp[3];
    float xf[16] = { xs0.x, xs0.y, xs0.z, xs0.w, xs1.x, xs1.y, xs1.z, xs1.w,
                     xs2.x, xs2.y, xs2.z, xs2.w, xs3.x, xs3.y, xs3.z, xs3.w };
    float L2v[2];
    #pragma unroll
    for (int h = 0; h < 2; ++h) {
        const float4* qt = (const float4*)(q + (size_t)t * 32 + h * 16);
        const float4* ks = (const float4*)(k + (size_t)s * 32 + h * 16);
        float4 a0 = qt[0], a1 = qt[1], a2 = qt[2], a3 = qt[3];
        float4 b0 = ks[0], c1 = ks[1], c2 = ks[2], c3 = ks[3];
        float dot = a0.x * b0.x + a0.y * b0.y + a0.z * b0.z + a0.w * b0.w
                  + a1.x * c1.x + a1.y * c1.y + a1.z * c1.z + a1.w * c1.w
                  + a2.x * c2.x + a2.y * c2.y + a2.z * c2.z + a2.w * c2.w
                  + a3.x * c3.x + a3.y * c3.y + a3.z * c3.z + a3.w * c3.w;
        float f = fh[h];
        float att = 0.0f;
        float acc[16];
        #pragma unroll
        for (int c = 0; c < 16; ++c) acc[c] = 0.0f;
        const float* w1b = W1 + h * 64;
        const float* b1b = b1 + h * 64;
        const float* wab = Wa + h * 64;
        const float* vcb = vC + h * 1024;
        #pragma unroll 8
        for (int j = 0; j < 64; ++j) {
            float hid = fmaxf(fmaf(f, w1b[j], b1b[j]), 0.0f);   // uniform scalars
            att = fmaf(hid, wab[j], att);
            #pragma unroll
            for (int c = 0; c < 16; ++c)
                acc[c] = fmaf(hid, vcb[j * 16 + c], acc[c]);     // uniform scalars
        }
        L2v[h] = fmaf(dot, 0.25f, att);
        // project to 8 outputs through Wo[h][0] (uniform scalars)
        float g[8];
        #pragma unroll
        for (int o = 0; o < 8; ++o) g[o] = 0.0f;
        const float* wob = Wo + h * 384;   // Wo[h][0][c][o] = Wo[h*384 + c*8 + o]
        #pragma unroll
        for (int c = 0; c < 16; ++c) {
            float axc = acc[c] * xf[c];
            #pragma unroll
            for (int o = 0; o < 8; ++o) g[o] = fmaf(axc, wob[c * 8 + o], g[o]);
        }
        if (ok) {
            gb[slot * 2 + h] = make_uint4(bf16pack2(g[0], g[1]), bf16pack2(g[2], g[3]),
                                          bf16pack2(g[4], g[5]), bf16pack2(g[6], g[7]));
        }
    }
    if (ok) *(float2*)(lgp + slot * 2) = make_float2(L2v[0], L2v[1]);
}

// wave per (node,head): 16 edge-groups x 4 lanes x 2 outputs (bf16x2 unpack),
// single-pass online softmax, -inf-safe merges.
__global__ __launch_bounds__(256) void k_gather(const int* __restrict__ deg,
        const float* __restrict__ lgp, const unsigned* __restrict__ gb,
        float* __restrict__ feat) {
    int t0 = threadIdx.x;
    int wv = t0 >> 6;                     // wave in block 0..3
    int lane = t0 & 63;
    int pid = blockIdx.x * 4 + wv;        // (node,head) pair; grid exact
    int n = pid >> 1, h = pid & 1;
    int dg = min(deg[n], CAP);
    int g = lane >> 2, p = lane & 3;      // group 0..15, uint index 0..3
    float m = -INFINITY, z = 0.0f, u0 = 0.0f, u1 = 0.0f;
    const float* lgb = lgp + (size_t)n * (CAP * 2) + h;
    const unsigned* gbb = gb + (size_t)n * (CAP * 8) + h * 4 + p;
    for (int i = g; i < dg; i += 16) {
        float L = lgb[i * 2];
        unsigned wbits = gbb[(size_t)i * 8];
        float ga = __uint_as_float(wbits << 16);
        float gbv = __uint_as_float(wbits & 0xffff0000u);
        float nm = fmaxf(m, L);
        float sc = (m > -INFINITY) ? __expf(m - nm) : 0.0f;
        float w  = __expf(L - nm);
        u0 = fmaf(u0, sc, w * ga);
        u1 = fmaf(u1, sc, w * gbv);
        z  = fmaf(z, sc, w);
        m = nm;
    }
    // merge the 16 groups (xor offs 4..32 preserve p bits)
    #pragma unroll
    for (int off = 4; off <= 32; off <<= 1) {
        float mo = __shfl_xor(m, off, 64);
        float zo = __shfl_xor(z, off, 64);
        float a0o = __shfl_xor(u0, off, 64);
        float a1o = __shfl_xor(u1, off, 64);
        float nm = fmaxf(m, mo);
        float a = (m  > -INFINITY) ? __expf(m  - nm) : 0.0f;
        float b = (mo > -INFINITY) ? __expf(mo - nm) : 0.0f;
        u0 = u0 * a + a0o * b;
        u1 = u1 * a + a1o * b;
        z  = z * a + zo * b;
        m = nm;
    }
    if (lane < 4) {
        float inv = (z > 0.0f) ? 1.0f / z : 0.0f;
        *(float2*)(feat + n * 16 + h * 8 + p * 2) = make_float2(u0 * inv, u1 * inv);
    }
}

// pooled[g][hc] += feat[n][hc] (run-length, batch sorted); last block to finish
// does the final 16x16 @ 16x32 matmul (ticket pattern, validated R9/R10).
// 80 blocks x 256: thread = (8-node segment, channel).
__global__ __launch_bounds__(256) void k_poolfinal(const float* __restrict__ feat,
        const int* __restrict__ batch, float* __restrict__ pooled,
        int* __restrict__ done, const float* __restrict__ Wproj,
        const float* __restrict__ bproj, float* __restrict__ out) {
    __shared__ float sP[256];
    int t = threadIdx.x;
    sP[t] = 0.0f;
    __syncthreads();
    int tid = blockIdx.x * 256 + t;        // 0..20479
    int c = tid & 15, seg = tid >> 4;      // seg 0..1279
    int n0 = seg * 8, n1 = min(n0 + 8, NN);
    float run = 0.0f;
    int curg = -1;
    for (int n = n0; n < n1; ++n) {
        int gg = batch[n];
        if (gg != curg) {
            if (curg >= 0) atomicAdd(&sP[curg * 16 + c], run);
            run = 0.0f; curg = gg;
        }
        run += feat[n * 16 + c];
    }
    if (curg >= 0) atomicAdd(&sP[curg * 16 + c], run);
    __syncthreads();
    atomicAdd(&pooled[t], sP[t]);
    __threadfence();
    __shared__ int lastBlk;
    if (t == 0) lastBlk = (atomicAdd(done, 1) == 79) ? 1 : 0;
    __syncthreads();
    if (!lastBlk) return;
    __shared__ float sPool[256];
    sPool[t] = atomicAdd(&pooled[t], 0.0f);   // coherent read of final values
    __syncthreads();
    for (int i = t; i < 512; i += 256) {
        int g = i >> 5, fo = i & 31;
        float acc = bproj[fo];
        #pragma unroll
        for (int j = 0; j < 16; ++j) acc = fmaf(sPool[g * 16 + j], Wproj[j * 32 + fo], acc);
        out[g * 32 + fo] = acc;
    }
}

extern "C" void kernel_launch(void* const* d_in, const int* in_sizes, int n_in,
                              void* d_out, int out_size, void* d_ws, size_t ws_size,
                              hipStream_t stream) {
    const float* nf    = (const float*)d_in[0];
    const float* pos   = (const float*)d_in[1];
    const float* We    = (const float*)d_in[2];
    const float* be    = (const float*)d_in[3];
    const float* Wq    = (const float*)d_in[4];
    const float* Wk    = (const float*)d_in[5];
    const float* W1    = (const float*)d_in[6];
    const float* b1    = (const float*)d_in[7];
    const float* Wa    = (const float*)d_in[8];
    const float* Wv    = (const float*)d_in[9];
    const float* Wo    = (const float*)d_in[10];
    const float* Wproj = (const float*)d_in[11];
    const float* bproj = (const float*)d_in[12];
    const int*   ei    = (const int*)d_in[13];
    const int*   batch = (const int*)d_in[14];
    float* out = (float*)d_out;
    (void)in_sizes; (void)n_in; (void)out_size; (void)ws_size;

    float* ws     = (float*)d_ws;
    float* x      = ws;                  // 160000
    float* q      = x + 160000;          // 320000
    float* k      = q + 320000;          // 320000
    float* feat   = k + 320000;          // 160000
    float* pooled = feat + 160000;       // 256
    int*   deg    = (int*)(pooled + 256);// 10000
    int*   done   = deg + 10000;         // 16
    float* vC     = (float*)(done + 16);         // 2048
    float* lgp    = vC + 2048;                   // 1,920,000
    unsigned* gbu = (unsigned*)(lgp + (size_t)NN * CAP * 2);  // 7,680,000 uints

    hipLaunchKernelGGL(k_xqk,      dim3(625),  dim3(256), 0, stream,
                       nf, We, be, Wq, Wk, Wv, x, q, k, (int*)pooled, vC);
    hipLaunchKernelGGL(k_edge,     dim3(625),  dim3(256), 0, stream,
                       pos, ei, q, k, W1, b1, Wa, vC, Wo, x, deg, lgp, (uint4*)gbu);
    hipLaunchKernelGGL(k_gather,   dim3(5000), dim3(256), 0, stream,
                       deg, lgp, gbu, feat);
    hipLaunchKernelGGL(k_poolfinal, dim3(80),  dim3(256), 0, stream,
                       feat, batch, pooled, done, Wproj, bproj, out);
}

// Round 6
// 132.316 us; speedup vs baseline: 3.3757x; 1.0161x over previous
//
#include <hip/hip_runtime.h>
#include <math.h>

#define NN 10000
#define NE 160000
#define CAP 96   // per-node edge bin capacity; deg ~ Poisson(16), +20 sigma
// Only the l=0 irrep reaches the output (scal takes cols h*72..h*72+8 of pooled,
// which come solely from node_out[:,:,0]; Y[:,0]==1). l=1/l=2 paths are dead.
//
// Round 13: measured-best R10 structure (131.8; band 130-134 across sessions).
// Single change: k_gather repacked 5000x256 -> 1250x1024 (same 20000 waves,
// same per-wave code, 4x fewer WG dispatches) to isolate dispatch overhead.
// k_poolfinal restored to R10's 40-block form (R12's 80-block was no better).
//
// Workspace (floats):
//   x      [10000][16]        @ 0
//   q      [10000][2][16]     @ 160000
//   k      [10000][2][16]     @ 480000
//   feat   [10000][16]        @ 800000
//   pooled [16][16]           @ 960000
//   deg    int[10000]         @ 960256   (pooled..deg..done zeroed together)
//   done   int[16]            @ 970256
//   vC     [2][64][16]        @ 970272   (compacted Wv[:, ::3])
//   lgp    [10000][96][2]     fp32 logits
//   gb     [10000][96][2][4]  uint bf16x2-packed g[8] per head

__device__ __forceinline__ unsigned bf16pack2(float a, float b) {
    unsigned ua = __float_as_uint(a);
    unsigned ub = __float_as_uint(b);
    ua = ua + 0x7fffu + ((ua >> 16) & 1u);
    ub = ub + 0x7fffu + ((ub >> 16) & 1u);
    return (ua >> 16) | (ub & 0xffff0000u);
}

// x = nf @ We + be ; q[h] = x @ Wq[h] ; k[h] = x @ Wk[h]
// block 0 also compacts Wv -> vC; all blocks zero pooled+deg+done.
__global__ __launch_bounds__(256) void k_xqk(const float* __restrict__ nf,
        const float* __restrict__ We, const float* __restrict__ be,
        const float* __restrict__ Wq, const float* __restrict__ Wk,
        const float* __restrict__ Wv,
        float* __restrict__ x, float* __restrict__ q, float* __restrict__ k,
        int* __restrict__ zeroReg, float* __restrict__ vC) {
    int t = threadIdx.x;
    int gid = blockIdx.x * 256 + t;
    if (gid < 10272) zeroReg[gid] = 0;   // pooled(256f)+deg(10000i)+done(16i)
    if (blockIdx.x == 0) {
        for (int i = t; i < 2048; i += 256) {
            int h = i >> 10, j = (i >> 4) & 63, c = i & 15;
            vC[i] = Wv[(h * 64 + j) * 48 + 3 * c];
        }
    }
    __shared__ float sWe[64 * 16];
    __shared__ float sWq[2 * 16 * 16];
    __shared__ float sWk[2 * 16 * 16];
    __shared__ float sNF[16 * 64];
    __shared__ float sX[16 * 16];
    for (int i = t; i < 1024; i += 256) sWe[i] = We[i];
    for (int i = t; i < 512; i += 256) { sWq[i] = Wq[i]; sWk[i] = Wk[i]; }
    int nodeBase = blockIdx.x * 16;
    for (int i = t; i < 1024; i += 256) {
        int n = nodeBase + (i >> 6);
        sNF[i] = (n < NN) ? nf[n * 64 + (i & 63)] : 0.0f;
    }
    __syncthreads();
    int ln = t >> 4, c = t & 15;
    int n = nodeBase + ln;
    float acc = be[c];
    #pragma unroll 16
    for (int j = 0; j < 64; ++j) acc = fmaf(sNF[ln * 64 + j], sWe[j * 16 + c], acc);
    sX[ln * 16 + c] = acc;
    __syncthreads();
    if (n < NN) {
        x[n * 16 + c] = acc;
        #pragma unroll
        for (int h = 0; h < 2; ++h) {
            float aq = 0.0f, ak = 0.0f;
            #pragma unroll
            for (int j = 0; j < 16; ++j) {
                float xv = sX[ln * 16 + j];
                aq = fmaf(xv, sWq[(h * 16 + j) * 16 + c], aq);
                ak = fmaf(xv, sWk[(h * 16 + j) * 16 + c], ak);
            }
            q[(n * 2 + h) * 16 + c] = aq;
            k[(n * 2 + h) * 16 + c] = ak;
        }
    }
}

// one thread per edge: logits + g[o] = ((hid@V) * x[src]) @ Wo, bin slot tgt*CAP+p.
// Weight reads are lane-invariant -> scalar s_loads. Payload bf16x2-packed.
__global__ __launch_bounds__(256) void k_edge(const float* __restrict__ pos,
        const int* __restrict__ ei,
        const float* __restrict__ q, const float* __restrict__ k,
        const float* __restrict__ W1, const float* __restrict__ b1,
        const float* __restrict__ Wa, const float* __restrict__ vC,
        const float* __restrict__ Wo,
        const float* __restrict__ x, int* __restrict__ deg,
        float* __restrict__ lgp, uint4* __restrict__ gb) {
    int e = blockIdx.x * 256 + threadIdx.x;
    if (e >= NE) return;
    int s = ei[e], t = ei[NE + e];
    int p = atomicAdd(&deg[t], 1);
    bool ok = (p < CAP);
    size_t slot = (size_t)t * CAP + p;
    float dx = pos[t * 3 + 0] - pos[s * 3 + 0];
    float dy = pos[t * 3 + 1] - pos[s * 3 + 1];
    float dz = pos[t * 3 + 2] - pos[s * 3 + 2];
    float d = sqrtf(dx * dx + dy * dy + dz * dz);
    float fh[2] = { d, 1.0f / (d * d) };
    const float4* xp = (const float4*)(x + (size_t)s * 16);
    float4 xs0 = xp[0], xs1 = xp[1], xs2 = xp[2], xs3 = xp[3];
    float xf[16] = { xs0.x, xs0.y, xs0.z, xs0.w, xs1.x, xs1.y, xs1.z, xs1.w,
                     xs2.x, xs2.y, xs2.z, xs2.w, xs3.x, xs3.y, xs3.z, xs3.w };
    float L2v[2];
    #pragma unroll
    for (int h = 0; h < 2; ++h) {
        const float4* qt = (const float4*)(q + (size_t)t * 32 + h * 16);
        const float4* ks = (const float4*)(k + (size_t)s * 32 + h * 16);
        float4 a0 = qt[0], a1 = qt[1], a2 = qt[2], a3 = qt[3];
        float4 b0 = ks[0], c1 = ks[1], c2 = ks[2], c3 = ks[3];
        float dot = a0.x * b0.x + a0.y * b0.y + a0.z * b0.z + a0.w * b0.w
                  + a1.x * c1.x + a1.y * c1.y + a1.z * c1.z + a1.w * c1.w
                  + a2.x * c2.x + a2.y * c2.y + a2.z * c2.z + a2.w * c2.w
                  + a3.x * c3.x + a3.y * c3.y + a3.z * c3.z + a3.w * c3.w;
        float f = fh[h];
        float att = 0.0f;
        float acc[16];
        #pragma unroll
        for (int c = 0; c < 16; ++c) acc[c] = 0.0f;
        const float* w1b = W1 + h * 64;
        const float* b1b = b1 + h * 64;
        const float* wab = Wa + h * 64;
        const float* vcb = vC + h * 1024;
        #pragma unroll 8
        for (int j = 0; j < 64; ++j) {
            float hid = fmaxf(fmaf(f, w1b[j], b1b[j]), 0.0f);   // uniform scalars
            att = fmaf(hid, wab[j], att);
            #pragma unroll
            for (int c = 0; c < 16; ++c)
                acc[c] = fmaf(hid, vcb[j * 16 + c], acc[c]);     // uniform scalars
        }
        L2v[h] = fmaf(dot, 0.25f, att);
        // project to 8 outputs through Wo[h][0] (uniform scalars)
        float g[8];
        #pragma unroll
        for (int o = 0; o < 8; ++o) g[o] = 0.0f;
        const float* wob = Wo + h * 384;   // Wo[h][0][c][o] = Wo[h*384 + c*8 + o]
        #pragma unroll
        for (int c = 0; c < 16; ++c) {
            float axc = acc[c] * xf[c];
            #pragma unroll
            for (int o = 0; o < 8; ++o) g[o] = fmaf(axc, wob[c * 8 + o], g[o]);
        }
        if (ok) {
            gb[slot * 2 + h] = make_uint4(bf16pack2(g[0], g[1]), bf16pack2(g[2], g[3]),
                                          bf16pack2(g[4], g[5]), bf16pack2(g[6], g[7]));
        }
    }
    if (ok) *(float2*)(lgp + slot * 2) = make_float2(L2v[0], L2v[1]);
}

// wave per (node,head): 16 edge-groups x 4 lanes x 2 outputs (bf16x2 unpack),
// single-pass online softmax, -inf-safe merges. 1024-thread blocks: 16 pids
// per block (same 20000 waves as before, 4x fewer WG dispatches).
__global__ __launch_bounds__(1024) void k_gather(const int* __restrict__ deg,
        const float* __restrict__ lgp, const unsigned* __restrict__ gb,
        float* __restrict__ feat) {
    int t0 = threadIdx.x;
    int wv = t0 >> 6;                     // wave in block 0..15
    int lane = t0 & 63;
    int pid = blockIdx.x * 16 + wv;       // (node,head) pair; grid exact
    int n = pid >> 1, h = pid & 1;
    int dg = min(deg[n], CAP);
    int g = lane >> 2, p = lane & 3;      // group 0..15, uint index 0..3
    float m = -INFINITY, z = 0.0f, u0 = 0.0f, u1 = 0.0f;
    const float* lgb = lgp + (size_t)n * (CAP * 2) + h;
    const unsigned* gbb = gb + (size_t)n * (CAP * 8) + h * 4 + p;
    for (int i = g; i < dg; i += 16) {
        float L = lgb[i * 2];
        unsigned wbits = gbb[(size_t)i * 8];
        float ga = __uint_as_float(wbits << 16);
        float gbv = __uint_as_float(wbits & 0xffff0000u);
        float nm = fmaxf(m, L);
        float sc = (m > -INFINITY) ? __expf(m - nm) : 0.0f;
        float w  = __expf(L - nm);
        u0 = fmaf(u0, sc, w * ga);
        u1 = fmaf(u1, sc, w * gbv);
        z  = fmaf(z, sc, w);
        m = nm;
    }
    // merge the 16 groups (xor offs 4..32 preserve p bits)
    #pragma unroll
    for (int off = 4; off <= 32; off <<= 1) {
        float mo = __shfl_xor(m, off, 64);
        float zo = __shfl_xor(z, off, 64);
        float a0o = __shfl_xor(u0, off, 64);
        float a1o = __shfl_xor(u1, off, 64);
        float nm = fmaxf(m, mo);
        float a = (m  > -INFINITY) ? __expf(m  - nm) : 0.0f;
        float b = (mo > -INFINITY) ? __expf(mo - nm) : 0.0f;
        u0 = u0 * a + a0o * b;
        u1 = u1 * a + a1o * b;
        z  = z * a + zo * b;
        m = nm;
    }
    if (lane < 4) {
        float inv = (z > 0.0f) ? 1.0f / z : 0.0f;
        *(float2*)(feat + n * 16 + h * 8 + p * 2) = make_float2(u0 * inv, u1 * inv);
    }
}

// pooled[g][hc] += feat[n][hc] (run-length, batch sorted); last block to finish
// does the final 16x16 @ 16x32 matmul (ticket pattern). R10 form: 40 blocks,
// 16-node segments, ticket 39.
__global__ __launch_bounds__(256) void k_poolfinal(const float* __restrict__ feat,
        const int* __restrict__ batch, float* __restrict__ pooled,
        int* __restrict__ done, const float* __restrict__ Wproj,
        const float* __restrict__ bproj, float* __restrict__ out) {
    __shared__ float sP[256];
    int t = threadIdx.x;
    sP[t] = 0.0f;
    __syncthreads();
    int tid = blockIdx.x * 256 + t;        // 0..10239
    int c = tid & 15, seg = tid >> 4;      // seg 0..639
    int n0 = seg * 16, n1 = min(n0 + 16, NN);
    float run = 0.0f;
    int curg = -1;
    for (int n = n0; n < n1; ++n) {
        int gg = batch[n];
        if (gg != curg) {
            if (curg >= 0) atomicAdd(&sP[curg * 16 + c], run);
            run = 0.0f; curg = gg;
        }
        run += feat[n * 16 + c];
    }
    if (curg >= 0) atomicAdd(&sP[curg * 16 + c], run);
    __syncthreads();
    atomicAdd(&pooled[t], sP[t]);
    __threadfence();
    __shared__ int lastBlk;
    if (t == 0) lastBlk = (atomicAdd(done, 1) == 39) ? 1 : 0;
    __syncthreads();
    if (!lastBlk) return;
    __shared__ float sPool[256];
    sPool[t] = atomicAdd(&pooled[t], 0.0f);   // coherent read of final values
    __syncthreads();
    for (int i = t; i < 512; i += 256) {
        int g = i >> 5, fo = i & 31;
        float acc = bproj[fo];
        #pragma unroll
        for (int j = 0; j < 16; ++j) acc = fmaf(sPool[g * 16 + j], Wproj[j * 32 + fo], acc);
        out[g * 32 + fo] = acc;
    }
}

extern "C" void kernel_launch(void* const* d_in, const int* in_sizes, int n_in,
                              void* d_out, int out_size, void* d_ws, size_t ws_size,
                              hipStream_t stream) {
    const float* nf    = (const float*)d_in[0];
    const float* pos   = (const float*)d_in[1];
    const float* We    = (const float*)d_in[2];
    const float* be    = (const float*)d_in[3];
    const float* Wq    = (const float*)d_in[4];
    const float* Wk    = (const float*)d_in[5];
    const float* W1    = (const float*)d_in[6];
    const float* b1    = (const float*)d_in[7];
    const float* Wa    = (const float*)d_in[8];
    const float* Wv    = (const float*)d_in[9];
    const float* Wo    = (const float*)d_in[10];
    const float* Wproj = (const float*)d_in[11];
    const float* bproj = (const float*)d_in[12];
    const int*   ei    = (const int*)d_in[13];
    const int*   batch = (const int*)d_in[14];
    float* out = (float*)d_out;
    (void)in_sizes; (void)n_in; (void)out_size; (void)ws_size;

    float* ws     = (float*)d_ws;
    float* x      = ws;                  // 160000
    float* q      = x + 160000;          // 320000
    float* k      = q + 320000;          // 320000
    float* feat   = k + 320000;          // 160000
    float* pooled = feat + 160000;       // 256
    int*   deg    = (int*)(pooled + 256);// 10000
    int*   done   = deg + 10000;         // 16
    float* vC     = (float*)(done + 16);         // 2048
    float* lgp    = vC + 2048;                   // 1,920,000
    unsigned* gbu = (unsigned*)(lgp + (size_t)NN * CAP * 2);  // 7,680,000 uints

    hipLaunchKernelGGL(k_xqk,      dim3(625),  dim3(256), 0, stream,
                       nf, We, be, Wq, Wk, Wv, x, q, k, (int*)pooled, vC);
    hipLaunchKernelGGL(k_edge,     dim3(625),  dim3(256), 0, stream,
                       pos, ei, q, k, W1, b1, Wa, vC, Wo, x, deg, lgp, (uint4*)gbu);
    hipLaunchKernelGGL(k_gather,   dim3(1250), dim3(1024), 0, stream,
                       deg, lgp, gbu, feat);
    hipLaunchKernelGGL(k_poolfinal, dim3(40),  dim3(256), 0, stream,
                       feat, batch, pooled, done, Wproj, bproj, out);
}